// Round 1
// baseline (154.228 us; speedup 1.0000x reference)
//
#include <hip/hip_runtime.h>
#include <math.h>

#define CONT_F 13
#define CATE_F 26
#define NF 39
#define EMB_D 40
#define NPAIR 741
#define VOCAB 100000
// LDS row stride in floats: 44 = 16B-aligned rows (176B) and (12*i+dc)%32 bank
// spread over 8 banks (stride 40 -> 4 banks = 16-way conflicts; 41 breaks float4).
#define XS_STRIDE 44

__device__ __forceinline__ void pair_from_p(int p, int& i, int& j) {
    int rem = p, ii = 0;
    while (rem >= 38 - ii) { rem -= 38 - ii; ++ii; }
    i = ii;
    j = ii + 1 + rem;
}

__global__ __launch_bounds__(256, 4)
void afm_fused_kernel(const float* __restrict__ conts,   // (B,13)
                      const int*   __restrict__ cates,   // (B,26)
                      const float* __restrict__ emb,     // (100000,40)
                      const float* __restrict__ attn_W,  // (8,40)
                      const float* __restrict__ attn_b,  // (8,)
                      const float* __restrict__ proj_W,  // (1,8)
                      const float* __restrict__ fc_W,    // (1,40)
                      const float* __restrict__ fc_b,    // (1,)
                      float* __restrict__ out)           // (B,1)
{
    __shared__ float xs[NF * XS_STRIDE];
    __shared__ float redm[4], reds[4], redg[4];

    const int tid = threadIdx.x;
    const int row = blockIdx.x;

    // ---------------- phase 1: stage x (39 x 40) into LDS -------------------
    // 390 float4 work items: 130 cont (emb rows 0..12 scaled by cont value),
    // 260 cate (gathered emb rows).
    const float4* emb4 = (const float4*)emb;
    for (int t = tid; t < 390; t += 256) {
        const int f = t / 10, q = t % 10;
        float4 v;
        if (f < CONT_F) {
            v = emb4[f * 10 + q];
            const float c = conts[row * CONT_F + f];
            v.x *= c; v.y *= c; v.z *= c; v.w *= c;
        } else {
            unsigned u = (unsigned)cates[row * CATE_F + (f - CONT_F)];
            if (u >= (unsigned)VOCAB) u = 0;  // safety clamp
            v = emb4[u * 10 + q];
        }
        *(float4*)&xs[f * XS_STRIDE + q * 4] = v;
    }
    __syncthreads();

    // ---------------- phase 2: 3 pairs per thread: logits + g ---------------
    // g_p = sum_d ewp[p][d] * fc_W[d]  (fc folded before the softmax-pool:
    // pooled @ fc_W^T == sum_p attn_p * g_p, exact up to fp reordering)
    int pi[3], pj[3];
    bool valid[3];
    {
        int p = 3 * tid, i, j;
        if (p < NPAIR) pair_from_p(p, i, j); else { i = 0; j = 1; }
        #pragma unroll
        for (int c = 0; c < 3; ++c) {
            valid[c] = (p + c) < NPAIR;
            pi[c] = i; pj[c] = j;
            if (++j > 38) { if (++i > 37) i = 0; j = i + 1; }
        }
    }

    float l[3], g[3];
    #pragma unroll
    for (int c = 0; c < 3; ++c) {
        const float* xi = &xs[pi[c] * XS_STRIDE];
        const float* xj = &xs[pj[c] * XS_STRIDE];
        float e[EMB_D];
        float gg = 0.f;
        #pragma unroll
        for (int dc = 0; dc < EMB_D; dc += 4) {
            const float4 a4 = *(const float4*)&xi[dc];
            const float4 b4 = *(const float4*)&xj[dc];
            e[dc + 0] = a4.x * b4.x;
            e[dc + 1] = a4.y * b4.y;
            e[dc + 2] = a4.z * b4.z;
            e[dc + 3] = a4.w * b4.w;
            // fc_W reads are block-uniform -> s_load into SGPRs
            gg += fc_W[dc + 0] * e[dc + 0];
            gg += fc_W[dc + 1] * e[dc + 1];
            gg += fc_W[dc + 2] * e[dc + 2];
            gg += fc_W[dc + 3] * e[dc + 3];
        }
        float lsum = 0.f;
        #pragma unroll
        for (int a = 0; a < 8; ++a) {
            float acc = attn_b[a];          // uniform -> SGPR
            #pragma unroll
            for (int d = 0; d < EMB_D; ++d)
                acc += attn_W[a * EMB_D + d] * e[d];  // uniform -> SGPR operand
            lsum += fmaxf(acc, 0.f) * proj_W[a];
        }
        l[c] = lsum;
        g[c] = gg;
    }

    // ---------------- phase 3: softmax over 741 pairs + epilogue ------------
    const int wid = tid >> 6;
    float m = -INFINITY;
    #pragma unroll
    for (int c = 0; c < 3; ++c) if (valid[c]) m = fmaxf(m, l[c]);
    #pragma unroll
    for (int off = 32; off; off >>= 1) m = fmaxf(m, __shfl_xor(m, off));
    if ((tid & 63) == 0) redm[wid] = m;
    __syncthreads();
    const float M = fmaxf(fmaxf(redm[0], redm[1]), fmaxf(redm[2], redm[3]));

    float s = 0.f, gs = 0.f;
    #pragma unroll
    for (int c = 0; c < 3; ++c) {
        if (valid[c]) {
            const float ee = __expf(l[c] - M);
            s += ee;
            gs += ee * g[c];
        }
    }
    #pragma unroll
    for (int off = 32; off; off >>= 1) {
        s  += __shfl_xor(s, off);
        gs += __shfl_xor(gs, off);
    }
    if ((tid & 63) == 0) { reds[wid] = s; redg[wid] = gs; }
    __syncthreads();

    if (tid == 0) {
        const float S = reds[0] + reds[1] + reds[2] + reds[3];
        const float G = redg[0] + redg[1] + redg[2] + redg[3];
        const float z = G / S + fc_b[0];
        out[row] = 1.f / (1.f + __expf(-z));
    }
}

extern "C" void kernel_launch(void* const* d_in, const int* in_sizes, int n_in,
                              void* d_out, int out_size, void* d_ws, size_t ws_size,
                              hipStream_t stream) {
    const float* conts  = (const float*)d_in[0];
    const int*   cates  = (const int*)  d_in[1];
    // d_in[2] = combs: unused by the reference computation
    const float* emb    = (const float*)d_in[3];
    const float* attn_W = (const float*)d_in[4];
    const float* attn_b = (const float*)d_in[5];
    const float* proj_W = (const float*)d_in[6];
    const float* fc_W   = (const float*)d_in[7];
    const float* fc_b   = (const float*)d_in[8];
    float* out = (float*)d_out;

    const int batch = in_sizes[0] / CONT_F;  // 4096
    afm_fused_kernel<<<batch, 256, 0, stream>>>(
        conts, cates, emb, attn_W, attn_b, proj_W, fc_W, fc_b, out);
}